// Round 4
// baseline (569.047 us; speedup 1.0000x reference)
//
#include <hip/hip_runtime.h>
#include <hip/hip_bf16.h>

typedef __hip_bfloat16 bf16;
typedef __attribute__((ext_vector_type(4))) float f32x4;
typedef __attribute__((ext_vector_type(8))) __bf16 bf16x8;

#define T_TOK 1024
#define HDIM 1024
#define FDIM 4096
#define NEXP 8
#define RLORA 16
#define LSCALE 2.0f

__device__ inline float b2f(bf16 v) { return __bfloat162float(v); }
__device__ inline bf16 f2b(float v) { return __float2bfloat16(v); }
__device__ inline ushort f2u(float v) { return __builtin_bit_cast(ushort, __float2bfloat16(v)); }

// ---------------- fp32 -> bf16 convert (x) ----------------
__global__ __launch_bounds__(256) void convert_kernel(
    const float* __restrict__ in, ushort* __restrict__ out, int n)
{
    int i = blockIdx.x * 256 + threadIdx.x;
    if (i * 4 < n) {
        const float4 v = *reinterpret_cast<const float4*>(in + i * 4);
        ushort4 o;
        o.x = f2u(v.x);
        o.y = f2u(v.y);
        o.z = f2u(v.z);
        o.w = f2u(v.w);
        *reinterpret_cast<ushort4*>(out + i * 4) = o;
    }
}

// ---------------- Router: logits, noisy logits, softmax+top2 (all fp32) -----
__global__ __launch_bounds__(256) void router_kernel(
    const float* __restrict__ x, const float* __restrict__ noise,
    const float* __restrict__ w_route, const float* __restrict__ w_noise,
    float* __restrict__ rl_out, int* __restrict__ SEL, float* __restrict__ WTS)
{
    const int t = blockIdx.x, tid = threadIdx.x;
    const float* xr = x + t * HDIM;
    float acc[16];
#pragma unroll
    for (int j = 0; j < 16; j++) acc[j] = 0.f;
    for (int h = tid; h < HDIM; h += 256) {
        float xv = xr[h];
        const float* wr = w_route + h * NEXP;
        const float* wn = w_noise + h * NEXP;
#pragma unroll
        for (int j = 0; j < 8; j++) acc[j] += xv * wr[j];
#pragma unroll
        for (int j = 0; j < 8; j++) acc[8 + j] += xv * wn[j];
    }
#pragma unroll
    for (int j = 0; j < 16; j++) {
        for (int off = 32; off > 0; off >>= 1) acc[j] += __shfl_down(acc[j], off, 64);
    }
    __shared__ float red[4][16];
    const int wave = tid >> 6, lane = tid & 63;
    if (lane == 0) {
#pragma unroll
        for (int j = 0; j < 16; j++) red[wave][j] = acc[j];
    }
    __syncthreads();
    if (tid == 0) {
        float rl[8];
#pragma unroll
        for (int j = 0; j < 8; j++) {
            float lg = red[0][j] + red[1][j] + red[2][j] + red[3][j];
            float nl = red[0][8 + j] + red[1][8 + j] + red[2][8 + j] + red[3][8 + j];
            float sp = fmaxf(nl, 0.f) + log1pf(expf(-fabsf(nl)));
            rl[j] = lg + noise[t * NEXP + j] * sp;
            rl_out[t * NEXP + j] = rl[j];
        }
        float m = rl[0];
#pragma unroll
        for (int j = 1; j < 8; j++) m = fmaxf(m, rl[j]);
        float p[8];
#pragma unroll
        for (int j = 0; j < 8; j++) p[j] = expf(rl[j] - m);
        int i1 = 0;
#pragma unroll
        for (int j = 1; j < 8; j++) if (p[j] > p[i1]) i1 = j;
        int i2 = (i1 == 0) ? 1 : 0;
#pragma unroll
        for (int j = 0; j < 8; j++) { if (j != i1 && p[j] > p[i2]) i2 = j; }
        float w1 = p[i1] / (p[i1] + p[i2]);
        float w2 = p[i2] / (p[i1] + p[i2]);
        SEL[t * 2 + 0] = i1; SEL[t * 2 + 1] = i2;
        WTS[t * 2 + 0] = w1; WTS[t * 2 + 1] = w2;
    }
}

// -------- Transpose + convert: fp32 [rows,cols] -> bf16 [cols,rows] ---------
__global__ __launch_bounds__(256) void transpose_kernel(
    const float* __restrict__ in, ushort* __restrict__ out, int rows, int cols)
{
    __shared__ float tile[32][33];
    const int bx = blockIdx.x * 32;  // col base
    const int by = blockIdx.y * 32;  // row base
    const int tx = threadIdx.x & 31, ty = threadIdx.x >> 5;  // 32 x 8
#pragma unroll
    for (int i = 0; i < 32; i += 8)
        tile[ty + i][tx] = in[(size_t)(by + ty + i) * cols + bx + tx];
    __syncthreads();
#pragma unroll
    for (int i = 0; i < 32; i += 8)
        out[(size_t)(bx + ty + i) * rows + by + tx] = f2u(tile[tx][ty + i]);
}

// ---------------- MFMA GEMM: C[M,N] (fp32) = A[M,K] * Bt[N,K]^T (bf16) ------
template <int BM, int BN>
__global__ __launch_bounds__(256) void gemm_bt(
    const ushort* __restrict__ A, const ushort* __restrict__ Bt,
    float* __restrict__ C, int M, int N, int Kd)
{
    constexpr int BK = 32;
    constexpr int PAD = 40;                 // padded K-stride (elements)
    constexpr int AIT = BM * BK / 2048;     // int4 stages per thread
    constexpr int BIT = BN * BK / 2048;
    constexpr int MF = BM / 32;             // 2x2 wave grid; wave owns BM/2 x BN/2
    constexpr int NF = BN / 32;
    __shared__ __align__(16) ushort sA[BM * PAD];
    __shared__ __align__(16) ushort sB[BN * PAD];

    const int tid = threadIdx.x;
    const int wave = tid >> 6, lane = tid & 63;
    const int wm = wave >> 1, wn = wave & 1;
    const int bm0 = blockIdx.y * BM, bn0 = blockIdx.x * BN;

    f32x4 acc[MF][NF];
#pragma unroll
    for (int m = 0; m < MF; m++)
#pragma unroll
        for (int n = 0; n < NF; n++) acc[m][n] = (f32x4){0.f, 0.f, 0.f, 0.f};

    int4 ra[AIT], rb[BIT];
#pragma unroll
    for (int i = 0; i < AIT; i++) {
        int idx = tid + i * 256; int r = idx >> 2, c = (idx & 3) * 8;
        ra[i] = *reinterpret_cast<const int4*>(A + (size_t)(bm0 + r) * Kd + c);
    }
#pragma unroll
    for (int i = 0; i < BIT; i++) {
        int idx = tid + i * 256; int r = idx >> 2, c = (idx & 3) * 8;
        rb[i] = *reinterpret_cast<const int4*>(Bt + (size_t)(bn0 + r) * Kd + c);
    }

    for (int k0 = 0; k0 < Kd; k0 += BK) {
        __syncthreads();
#pragma unroll
        for (int i = 0; i < AIT; i++) {
            int idx = tid + i * 256; int r = idx >> 2, c = (idx & 3) * 8;
            *reinterpret_cast<int4*>(&sA[r * PAD + c]) = ra[i];
        }
#pragma unroll
        for (int i = 0; i < BIT; i++) {
            int idx = tid + i * 256; int r = idx >> 2, c = (idx & 3) * 8;
            *reinterpret_cast<int4*>(&sB[r * PAD + c]) = rb[i];
        }
        __syncthreads();
        const int k1 = k0 + BK;
        if (k1 < Kd) {
#pragma unroll
            for (int i = 0; i < AIT; i++) {
                int idx = tid + i * 256; int r = idx >> 2, c = (idx & 3) * 8;
                ra[i] = *reinterpret_cast<const int4*>(A + (size_t)(bm0 + r) * Kd + k1 + c);
            }
#pragma unroll
            for (int i = 0; i < BIT; i++) {
                int idx = tid + i * 256; int r = idx >> 2, c = (idx & 3) * 8;
                rb[i] = *reinterpret_cast<const int4*>(Bt + (size_t)(bn0 + r) * Kd + k1 + c);
            }
        }
        const int rg = lane & 15, kg = (lane >> 4) * 8;
        bf16x8 af[MF], bfr[NF];
#pragma unroll
        for (int m = 0; m < MF; m++) {
            int row = wm * (BM / 2) + m * 16 + rg;
            af[m] = *reinterpret_cast<const bf16x8*>(&sA[row * PAD + kg]);
        }
#pragma unroll
        for (int n = 0; n < NF; n++) {
            int row = wn * (BN / 2) + n * 16 + rg;
            bfr[n] = *reinterpret_cast<const bf16x8*>(&sB[row * PAD + kg]);
        }
#pragma unroll
        for (int m = 0; m < MF; m++)
#pragma unroll
            for (int n = 0; n < NF; n++)
                acc[m][n] = __builtin_amdgcn_mfma_f32_16x16x32_bf16(af[m], bfr[n], acc[m][n], 0, 0, 0);
    }

    const int rg = lane & 15, qg = lane >> 4;
#pragma unroll
    for (int m = 0; m < MF; m++) {
#pragma unroll
        for (int n = 0; n < NF; n++) {
            int row0 = bm0 + wm * (BM / 2) + m * 16 + qg * 4;
            int col = bn0 + wn * (BN / 2) + n * 16 + rg;
#pragma unroll
            for (int j = 0; j < 4; j++)
                C[(size_t)(row0 + j) * N + col] = acc[m][n][j];
        }
    }
}

// ---------------- LoRA gate/up + SiLU -> ACT (per token, both slots) --------
__global__ __launch_bounds__(256) void act_kernel(
    const float* __restrict__ x, const float* __restrict__ G, const float* __restrict__ U,
    const float* __restrict__ a_gate, const float* __restrict__ b_gate,
    const float* __restrict__ a_up, const float* __restrict__ b_up,
    const int* __restrict__ SEL, bf16* __restrict__ ACT)
{
    const int t = blockIdx.x, tid = threadIdx.x;
    __shared__ float xs[HDIM];
    __shared__ float red[64][4];
    __shared__ float xa_s[64];

    for (int i = tid; i < HDIM; i += 256) xs[i] = x[t * HDIM + i];
    __syncthreads();
    const int e0 = SEL[t * 2 + 0], e1 = SEL[t * 2 + 1];
    // 64 rank-dots: d = slot*32 + mat*16 + r over H, split in 4 chunks
    const int d = tid & 63, q = tid >> 6;
    const int slot = d >> 5, mat = (d >> 4) & 1, r = d & 15;
    const int e = slot ? e1 : e0;
    const float* Am = (mat ? a_up : a_gate) + (size_t)e * HDIM * RLORA;
    float s = 0.f;
    const int h0 = q * 256;
    for (int h = h0; h < h0 + 256; ++h) s += xs[h] * Am[h * RLORA + r];
    red[d][q] = s;
    __syncthreads();
    if (tid < 64) xa_s[tid] = red[tid][0] + red[tid][1] + red[tid][2] + red[tid][3];
    __syncthreads();

    for (int f = tid; f < FDIM; f += 256) {
        float gsh = G[(size_t)t * FDIM + f], ush = U[(size_t)t * FDIM + f];
#pragma unroll
        for (int k = 0; k < 2; k++) {
            int ek = k ? e1 : e0;
            const float* Bg = b_gate + (size_t)ek * RLORA * FDIM;
            const float* Bu = b_up + (size_t)ek * RLORA * FDIM;
            float lg = 0.f, lu = 0.f;
#pragma unroll
            for (int rr = 0; rr < 16; rr++) {
                lg += xa_s[k * 32 + rr] * Bg[rr * FDIM + f];
                lu += xa_s[k * 32 + 16 + rr] * Bu[rr * FDIM + f];
            }
            float gate = gsh + LSCALE * lg;
            float up = ush + LSCALE * lu;
            float a = (gate / (1.f + expf(-gate))) * up;
            ACT[(size_t)(t * 2 + k) * FDIM + f] = f2b(a);
        }
    }
}

// ---------------- LoRA down correction: DOWN += 2*(ACT@a_down)@b_down -------
__global__ __launch_bounds__(256) void lora_down_kernel(
    const bf16* __restrict__ ACT, const float* __restrict__ a_down,
    const float* __restrict__ b_down, const int* __restrict__ SEL,
    float* __restrict__ DOWN)
{
    const int p = blockIdx.x, tid = threadIdx.x;
    const int t = p >> 1, k = p & 1;
    const int e = SEL[t * 2 + k];
    __shared__ float red[16][17];
    __shared__ float ad[16];
    const int r = tid & 15, chunk = tid >> 4;
    const float* Ad = a_down + (size_t)e * FDIM * RLORA;
    const bf16* ap = ACT + (size_t)p * FDIM;
    float s = 0.f;
    const int f0 = chunk * 256;
    for (int f = f0; f < f0 + 256; ++f) s += b2f(ap[f]) * Ad[f * RLORA + r];
    red[r][chunk] = s;
    __syncthreads();
    if (tid < 16) {
        float v = 0.f;
        for (int c = 0; c < 16; c++) v += red[tid][c];
        ad[tid] = v;
    }
    __syncthreads();
    const float* Bd = b_down + (size_t)e * RLORA * HDIM;
    for (int h = tid; h < HDIM; h += 256) {
        float v = 0.f;
#pragma unroll
        for (int rr = 0; rr < 16; rr++) v += ad[rr] * Bd[rr * HDIM + h];
        DOWN[(size_t)p * HDIM + h] += 2.0f * v;
    }
}

// ---------------- Combine: out[t] = w0*DOWN[2t] + w1*DOWN[2t+1] -------------
__global__ __launch_bounds__(256) void combine_kernel(
    const float* __restrict__ DOWN, const float* __restrict__ WTS, float* __restrict__ out)
{
    const int t = blockIdx.x, tid = threadIdx.x;
    const float w0 = WTS[t * 2 + 0], w1 = WTS[t * 2 + 1];
    for (int h = tid; h < HDIM; h += 256)
        out[(size_t)t * HDIM + h] =
            w0 * DOWN[(size_t)(2 * t) * HDIM + h] + w1 * DOWN[(size_t)(2 * t + 1) * HDIM + h];
}

extern "C" void kernel_launch(void* const* d_in, const int* in_sizes, int n_in,
                              void* d_out, int out_size, void* d_ws, size_t ws_size,
                              hipStream_t stream) {
    (void)in_sizes; (void)n_in; (void)out_size; (void)ws_size;
    const float* x       = (const float*)d_in[0];
    const float* noise   = (const float*)d_in[1];
    const float* w_route = (const float*)d_in[2];
    const float* w_noise = (const float*)d_in[3];
    const float* w_gate  = (const float*)d_in[4];
    const float* w_up    = (const float*)d_in[5];
    const float* w_down  = (const float*)d_in[6];
    const float* a_gate  = (const float*)d_in[7];
    const float* b_gate  = (const float*)d_in[8];
    const float* a_up    = (const float*)d_in[9];
    const float* b_up    = (const float*)d_in[10];
    const float* a_down  = (const float*)d_in[11];
    const float* b_down  = (const float*)d_in[12];
    float* out    = (float*)d_out;
    float* rl_out = out + (size_t)T_TOK * HDIM;

    char* ws = (char*)d_ws;
    float*  G    = (float*)(ws);                          // 16 MB [T,F]
    float*  U    = (float*)(ws + (size_t)(16 << 20));     // 16 MB [T,F]
    ushort* WgT  = (ushort*)(ws + (size_t)(32 << 20));    // 8 MB  [F,H] bf16
    ushort* WuT  = (ushort*)(ws + (size_t)(40 << 20));    // 8 MB  [F,H] bf16
    ushort* WdT  = (ushort*)(ws + (size_t)(48 << 20));    // 8 MB  [H,F] bf16
    bf16*   ACT  = (bf16*)(ws + (size_t)(56 << 20));      // 16 MB [2048,F] bf16
    float*  DOWN = (float*)(ws + (size_t)(72 << 20));     // 8 MB  [2048,H]
    ushort* XB   = (ushort*)(ws + (size_t)(80 << 20));    // 2 MB  [T,H] bf16
    int*    SEL  = (int*)(ws + (size_t)(83 << 20));
    float*  WTS  = (float*)(ws + (size_t)(83 << 20) + 8192);

    router_kernel<<<T_TOK, 256, 0, stream>>>(x, noise, w_route, w_noise, rl_out, SEL, WTS);

    convert_kernel<<<(T_TOK * HDIM / 4 + 255) / 256, 256, 0, stream>>>(x, XB, T_TOK * HDIM);

    transpose_kernel<<<dim3(FDIM / 32, HDIM / 32), 256, 0, stream>>>(w_gate, WgT, HDIM, FDIM);
    transpose_kernel<<<dim3(FDIM / 32, HDIM / 32), 256, 0, stream>>>(w_up, WuT, HDIM, FDIM);
    transpose_kernel<<<dim3(HDIM / 32, FDIM / 32), 256, 0, stream>>>(w_down, WdT, FDIM, HDIM);

    gemm_bt<64, 128><<<dim3(FDIM / 128, T_TOK / 64), 256, 0, stream>>>(XB, WgT, G, T_TOK, FDIM, HDIM);
    gemm_bt<64, 128><<<dim3(FDIM / 128, T_TOK / 64), 256, 0, stream>>>(XB, WuT, U, T_TOK, FDIM, HDIM);

    act_kernel<<<T_TOK, 256, 0, stream>>>(x, G, U, a_gate, b_gate, a_up, b_up, SEL, ACT);

    gemm_bt<64, 64><<<dim3(HDIM / 64, 2 * T_TOK / 64), 256, 0, stream>>>((const ushort*)ACT, WdT, DOWN, 2 * T_TOK, HDIM, FDIM);

    lora_down_kernel<<<2 * T_TOK, 256, 0, stream>>>(ACT, a_down, b_down, SEL, DOWN);

    combine_kernel<<<T_TOK, 256, 0, stream>>>(DOWN, WTS, out);
}

// Round 5
// 295.839 us; speedup vs baseline: 1.9235x; 1.9235x over previous
//
#include <hip/hip_runtime.h>
#include <hip/hip_bf16.h>

typedef __hip_bfloat16 bf16;
typedef __attribute__((ext_vector_type(4))) float f32x4;
typedef __attribute__((ext_vector_type(8))) __bf16 bf16x8;

#define T_TOK 1024
#define HDIM 1024
#define FDIM 4096
#define NEXP 8
#define RLORA 16
#define LSCALE 2.0f

__device__ inline float b2f(bf16 v) { return __bfloat162float(v); }
__device__ inline bf16 f2b(float v) { return __float2bfloat16(v); }
__device__ inline ushort f2u(float v) { return __builtin_bit_cast(ushort, __float2bfloat16(v)); }

// ---------------- fp32 -> bf16 convert (x) ----------------
__global__ __launch_bounds__(256) void convert_kernel(
    const float* __restrict__ in, ushort* __restrict__ out, int n)
{
    int i = blockIdx.x * 256 + threadIdx.x;
    if (i * 4 < n) {
        const float4 v = *reinterpret_cast<const float4*>(in + i * 4);
        ushort4 o;
        o.x = f2u(v.x);
        o.y = f2u(v.y);
        o.z = f2u(v.z);
        o.w = f2u(v.w);
        *reinterpret_cast<ushort4*>(out + i * 4) = o;
    }
}

// ---------------- Router: logits, noisy logits, softmax+top2 (all fp32) -----
__global__ __launch_bounds__(256) void router_kernel(
    const float* __restrict__ x, const float* __restrict__ noise,
    const float* __restrict__ w_route, const float* __restrict__ w_noise,
    float* __restrict__ rl_out, int* __restrict__ SEL, float* __restrict__ WTS)
{
    const int t = blockIdx.x, tid = threadIdx.x;
    const float* xr = x + t * HDIM;
    float acc[16];
#pragma unroll
    for (int j = 0; j < 16; j++) acc[j] = 0.f;
    for (int h = tid; h < HDIM; h += 256) {
        float xv = xr[h];
        const float* wr = w_route + h * NEXP;
        const float* wn = w_noise + h * NEXP;
#pragma unroll
        for (int j = 0; j < 8; j++) acc[j] += xv * wr[j];
#pragma unroll
        for (int j = 0; j < 8; j++) acc[8 + j] += xv * wn[j];
    }
#pragma unroll
    for (int j = 0; j < 16; j++) {
        for (int off = 32; off > 0; off >>= 1) acc[j] += __shfl_down(acc[j], off, 64);
    }
    __shared__ float red[4][16];
    const int wave = tid >> 6, lane = tid & 63;
    if (lane == 0) {
#pragma unroll
        for (int j = 0; j < 16; j++) red[wave][j] = acc[j];
    }
    __syncthreads();
    if (tid == 0) {
        float rl[8];
#pragma unroll
        for (int j = 0; j < 8; j++) {
            float lg = red[0][j] + red[1][j] + red[2][j] + red[3][j];
            float nl = red[0][8 + j] + red[1][8 + j] + red[2][8 + j] + red[3][8 + j];
            float sp = fmaxf(nl, 0.f) + log1pf(expf(-fabsf(nl)));
            rl[j] = lg + noise[t * NEXP + j] * sp;
            rl_out[t * NEXP + j] = rl[j];
        }
        float m = rl[0];
#pragma unroll
        for (int j = 1; j < 8; j++) m = fmaxf(m, rl[j]);
        float p[8];
#pragma unroll
        for (int j = 0; j < 8; j++) p[j] = expf(rl[j] - m);
        int i1 = 0;
#pragma unroll
        for (int j = 1; j < 8; j++) if (p[j] > p[i1]) i1 = j;
        int i2 = (i1 == 0) ? 1 : 0;
#pragma unroll
        for (int j = 0; j < 8; j++) { if (j != i1 && p[j] > p[i2]) i2 = j; }
        float w1 = p[i1] / (p[i1] + p[i2]);
        float w2 = p[i2] / (p[i1] + p[i2]);
        SEL[t * 2 + 0] = i1; SEL[t * 2 + 1] = i2;
        WTS[t * 2 + 0] = w1; WTS[t * 2 + 1] = w2;
    }
}

// ---------------- Build per-expert (token,slot) lists via atomics -----------
__global__ __launch_bounds__(256) void build_lists_kernel(
    const int* __restrict__ SEL, int* __restrict__ CNT, int* __restrict__ LIST)
{
    const int p = blockIdx.x * 256 + threadIdx.x;  // 0..2047
    const int e = SEL[p];
    const int idx = atomicAdd(&CNT[e], 1);
    LIST[e * 2048 + idx] = p;
}

// -------- Transpose + convert: fp32 [rows,cols] -> bf16 [cols,rows] ---------
__global__ __launch_bounds__(256) void transpose_kernel(
    const float* __restrict__ in, ushort* __restrict__ out, int rows, int cols)
{
    __shared__ float tile[32][33];
    const int bx = blockIdx.x * 32;  // col base
    const int by = blockIdx.y * 32;  // row base
    const int tx = threadIdx.x & 31, ty = threadIdx.x >> 5;  // 32 x 8
#pragma unroll
    for (int i = 0; i < 32; i += 8)
        tile[ty + i][tx] = in[(size_t)(by + ty + i) * cols + bx + tx];
    __syncthreads();
#pragma unroll
    for (int i = 0; i < 32; i += 8)
        out[(size_t)(bx + ty + i) * rows + by + tx] = f2u(tile[tx][ty + i]);
}

// -------- Pack LoRA-A (gate/up) into AT[256][H] bf16, row = e*32+mat*16+r ---
__global__ __launch_bounds__(256) void at_gu_kernel(
    const float* __restrict__ a_gate, const float* __restrict__ a_up,
    ushort* __restrict__ AT)
{
    const int row = blockIdx.x;  // 0..255
    const int e = row >> 5, mat = (row >> 4) & 1, r = row & 15;
    const float* src = (mat ? a_up : a_gate) + (size_t)e * HDIM * RLORA;
    for (int h = threadIdx.x; h < HDIM; h += 256)
        AT[(size_t)row * HDIM + h] = f2u(src[h * RLORA + r]);
}

// -------- Pack a_down into AdT[128][F] bf16, row = e*16+r -------------------
__global__ __launch_bounds__(256) void adt_kernel(
    const float* __restrict__ a_down, ushort* __restrict__ AdT)
{
    const int row = blockIdx.x;  // 0..127
    const int e = row >> 4, r = row & 15;
    const float* src = a_down + (size_t)e * FDIM * RLORA;
    for (int f = threadIdx.x; f < FDIM; f += 256)
        AdT[(size_t)row * FDIM + f] = f2u(src[f * RLORA + r]);
}

// ---------------- MFMA GEMM: C[M,N] (fp32) = A[M,K] * Bt[N,K]^T (bf16) ------
template <int BM, int BN>
__global__ __launch_bounds__(256) void gemm_bt(
    const ushort* __restrict__ A, const ushort* __restrict__ Bt,
    float* __restrict__ C, int M, int N, int Kd)
{
    constexpr int BK = 32;
    constexpr int PAD = 40;                 // padded K-stride (elements)
    constexpr int AIT = BM * BK / 2048;     // int4 stages per thread
    constexpr int BIT = BN * BK / 2048;
    constexpr int MF = BM / 32;             // 2x2 wave grid; wave owns BM/2 x BN/2
    constexpr int NF = BN / 32;
    __shared__ __align__(16) ushort sA[BM * PAD];
    __shared__ __align__(16) ushort sB[BN * PAD];

    const int tid = threadIdx.x;
    const int wave = tid >> 6, lane = tid & 63;
    const int wm = wave >> 1, wn = wave & 1;
    const int bm0 = blockIdx.y * BM, bn0 = blockIdx.x * BN;

    f32x4 acc[MF][NF];
#pragma unroll
    for (int m = 0; m < MF; m++)
#pragma unroll
        for (int n = 0; n < NF; n++) acc[m][n] = (f32x4){0.f, 0.f, 0.f, 0.f};

    int4 ra[AIT], rb[BIT];
#pragma unroll
    for (int i = 0; i < AIT; i++) {
        int idx = tid + i * 256; int r = idx >> 2, c = (idx & 3) * 8;
        ra[i] = *reinterpret_cast<const int4*>(A + (size_t)(bm0 + r) * Kd + c);
    }
#pragma unroll
    for (int i = 0; i < BIT; i++) {
        int idx = tid + i * 256; int r = idx >> 2, c = (idx & 3) * 8;
        rb[i] = *reinterpret_cast<const int4*>(Bt + (size_t)(bn0 + r) * Kd + c);
    }

    for (int k0 = 0; k0 < Kd; k0 += BK) {
        __syncthreads();
#pragma unroll
        for (int i = 0; i < AIT; i++) {
            int idx = tid + i * 256; int r = idx >> 2, c = (idx & 3) * 8;
            *reinterpret_cast<int4*>(&sA[r * PAD + c]) = ra[i];
        }
#pragma unroll
        for (int i = 0; i < BIT; i++) {
            int idx = tid + i * 256; int r = idx >> 2, c = (idx & 3) * 8;
            *reinterpret_cast<int4*>(&sB[r * PAD + c]) = rb[i];
        }
        __syncthreads();
        const int k1 = k0 + BK;
        if (k1 < Kd) {
#pragma unroll
            for (int i = 0; i < AIT; i++) {
                int idx = tid + i * 256; int r = idx >> 2, c = (idx & 3) * 8;
                ra[i] = *reinterpret_cast<const int4*>(A + (size_t)(bm0 + r) * Kd + k1 + c);
            }
#pragma unroll
            for (int i = 0; i < BIT; i++) {
                int idx = tid + i * 256; int r = idx >> 2, c = (idx & 3) * 8;
                rb[i] = *reinterpret_cast<const int4*>(Bt + (size_t)(bn0 + r) * Kd + k1 + c);
            }
        }
        const int rg = lane & 15, kg = (lane >> 4) * 8;
        bf16x8 af[MF], bfr[NF];
#pragma unroll
        for (int m = 0; m < MF; m++) {
            int row = wm * (BM / 2) + m * 16 + rg;
            af[m] = *reinterpret_cast<const bf16x8*>(&sA[row * PAD + kg]);
        }
#pragma unroll
        for (int n = 0; n < NF; n++) {
            int row = wn * (BN / 2) + n * 16 + rg;
            bfr[n] = *reinterpret_cast<const bf16x8*>(&sB[row * PAD + kg]);
        }
#pragma unroll
        for (int m = 0; m < MF; m++)
#pragma unroll
            for (int n = 0; n < NF; n++)
                acc[m][n] = __builtin_amdgcn_mfma_f32_16x16x32_bf16(af[m], bfr[n], acc[m][n], 0, 0, 0);
    }

    const int rg = lane & 15, qg = lane >> 4;
#pragma unroll
    for (int m = 0; m < MF; m++) {
#pragma unroll
        for (int n = 0; n < NF; n++) {
            int row0 = bm0 + wm * (BM / 2) + m * 16 + qg * 4;
            int col = bn0 + wn * (BN / 2) + n * 16 + rg;
#pragma unroll
            for (int j = 0; j < 4; j++)
                C[(size_t)(row0 + j) * N + col] = acc[m][n][j];
        }
    }
}

// -------- Expert-grouped LoRA gate/up + SiLU epilogue -> ACT ----------------
// grid (NEXP, FDIM/256, NCHUNK); block 256; B tiles staged in LDS once/block.
#define NCHUNK 8
__global__ __launch_bounds__(256) void act2_kernel(
    const float* __restrict__ G, const float* __restrict__ U,
    const float* __restrict__ XA,
    const float* __restrict__ b_gate, const float* __restrict__ b_up,
    const int* __restrict__ CNT, const int* __restrict__ LIST,
    bf16* __restrict__ ACT)
{
    const int e = blockIdx.x, f0 = blockIdx.y * 256, chunk = blockIdx.z;
    const int tid = threadIdx.x;
    __shared__ float sBg[16][256];
    __shared__ float sBu[16][256];
    __shared__ float xa_s[2][32];

    const float* bg = b_gate + (size_t)e * RLORA * FDIM + f0;
    const float* bu = b_up + (size_t)e * RLORA * FDIM + f0;
#pragma unroll
    for (int r = 0; r < 16; r++) {
        sBg[r][tid] = bg[(size_t)r * FDIM + tid];
        sBu[r][tid] = bu[(size_t)r * FDIM + tid];
    }
    __syncthreads();

    const int n = CNT[e];
    int j = 0;
    for (int i = chunk; i < n; i += NCHUNK, ++j) {
        const int p = LIST[e * 2048 + i];
        const int t = p >> 1;
        const int buf = j & 1;
        if (tid < 32) xa_s[buf][tid] = XA[(size_t)t * 256 + e * 32 + tid];
        __syncthreads();
        const float g = G[(size_t)t * FDIM + f0 + tid];
        const float u = U[(size_t)t * FDIM + f0 + tid];
        float lg = 0.f, lu = 0.f;
#pragma unroll
        for (int r = 0; r < 16; r++) {
            lg += xa_s[buf][r] * sBg[r][tid];
            lu += xa_s[buf][16 + r] * sBu[r][tid];
        }
        const float gate = g + LSCALE * lg;
        const float up = u + LSCALE * lu;
        ACT[(size_t)p * FDIM + f0 + tid] = f2b((gate / (1.f + expf(-gate))) * up);
    }
}

// -------- Combine: out[t] = sum_k wk*(DOWN[p] + 2*AD[p]·b_down[e_k]) --------
__global__ __launch_bounds__(256) void combine2_kernel(
    const float* __restrict__ DOWN, const float* __restrict__ AD,
    const float* __restrict__ b_down, const int* __restrict__ SEL,
    const float* __restrict__ WTS, float* __restrict__ out)
{
    const int t = blockIdx.x, tid = threadIdx.x;
    const int e0 = SEL[t * 2 + 0], e1 = SEL[t * 2 + 1];
    const float w0 = WTS[t * 2 + 0], w1 = WTS[t * 2 + 1];
    __shared__ float ad0[16], ad1[16];
    if (tid < 16) ad0[tid] = AD[(size_t)(2 * t) * 128 + e0 * 16 + tid];
    else if (tid < 32) ad1[tid - 16] = AD[(size_t)(2 * t + 1) * 128 + e1 * 16 + (tid - 16)];
    __syncthreads();
    const float* B0 = b_down + (size_t)e0 * RLORA * HDIM;
    const float* B1 = b_down + (size_t)e1 * RLORA * HDIM;
    for (int h = tid; h < HDIM; h += 256) {
        float v0 = DOWN[(size_t)(2 * t) * HDIM + h];
        float v1 = DOWN[(size_t)(2 * t + 1) * HDIM + h];
        float l0 = 0.f, l1 = 0.f;
#pragma unroll
        for (int r = 0; r < 16; r++) {
            l0 += ad0[r] * B0[r * HDIM + h];
            l1 += ad1[r] * B1[r * HDIM + h];
        }
        out[(size_t)t * HDIM + h] = w0 * (v0 + LSCALE * l0) + w1 * (v1 + LSCALE * l1);
    }
}

extern "C" void kernel_launch(void* const* d_in, const int* in_sizes, int n_in,
                              void* d_out, int out_size, void* d_ws, size_t ws_size,
                              hipStream_t stream) {
    (void)in_sizes; (void)n_in; (void)out_size; (void)ws_size;
    const float* x       = (const float*)d_in[0];
    const float* noise   = (const float*)d_in[1];
    const float* w_route = (const float*)d_in[2];
    const float* w_noise = (const float*)d_in[3];
    const float* w_gate  = (const float*)d_in[4];
    const float* w_up    = (const float*)d_in[5];
    const float* w_down  = (const float*)d_in[6];
    const float* a_gate  = (const float*)d_in[7];
    const float* b_gate  = (const float*)d_in[8];
    const float* a_up    = (const float*)d_in[9];
    const float* b_up    = (const float*)d_in[10];
    const float* a_down  = (const float*)d_in[11];
    const float* b_down  = (const float*)d_in[12];
    float* out    = (float*)d_out;
    float* rl_out = out + (size_t)T_TOK * HDIM;

    char* ws = (char*)d_ws;
    float*  G    = (float*)(ws);                          // 16 MB [T,F]
    float*  U    = (float*)(ws + (size_t)(16 << 20));     // 16 MB [T,F]
    ushort* WgT  = (ushort*)(ws + (size_t)(32 << 20));    // 8 MB  [F,H] bf16
    ushort* WuT  = (ushort*)(ws + (size_t)(40 << 20));    // 8 MB  [F,H] bf16
    ushort* WdT  = (ushort*)(ws + (size_t)(48 << 20));    // 8 MB  [H,F] bf16
    bf16*   ACT  = (bf16*)(ws + (size_t)(56 << 20));      // 16 MB [2048,F] bf16
    float*  DOWN = (float*)(ws + (size_t)(72 << 20));     // 8 MB  [2048,H]
    ushort* XB   = (ushort*)(ws + (size_t)(80 << 20));    // 2 MB  [T,H] bf16
    ushort* ATgu = (ushort*)(ws + (size_t)(82 << 20));    // 0.5MB [256,H] bf16
    ushort* AdT  = (ushort*)(ws + (size_t)(83 << 20));    // 1 MB  [128,F] bf16
    float*  XA   = (float*)(ws + (size_t)(84 << 20));     // 1 MB  [T,256]
    float*  AD   = (float*)(ws + (size_t)(85 << 20));     // 1 MB  [2048,128]
    int*    LIST = (int*)(ws + (size_t)(86 << 20));       // 64 KB [8][2048]
    int*    CNT  = (int*)(ws + (size_t)(87 << 20));       // 32 B
    int*    SEL  = (int*)(ws + (size_t)(87 << 20) + 4096);
    float*  WTS  = (float*)(ws + (size_t)(87 << 20) + 16384);

    hipMemsetAsync(CNT, 0, NEXP * sizeof(int), stream);

    router_kernel<<<T_TOK, 256, 0, stream>>>(x, noise, w_route, w_noise, rl_out, SEL, WTS);
    build_lists_kernel<<<2 * T_TOK / 256, 256, 0, stream>>>(SEL, CNT, LIST);

    convert_kernel<<<(T_TOK * HDIM / 4 + 255) / 256, 256, 0, stream>>>(x, XB, T_TOK * HDIM);

    transpose_kernel<<<dim3(FDIM / 32, HDIM / 32), 256, 0, stream>>>(w_gate, WgT, HDIM, FDIM);
    transpose_kernel<<<dim3(FDIM / 32, HDIM / 32), 256, 0, stream>>>(w_up, WuT, HDIM, FDIM);
    transpose_kernel<<<dim3(HDIM / 32, FDIM / 32), 256, 0, stream>>>(w_down, WdT, FDIM, HDIM);
    at_gu_kernel<<<256, 256, 0, stream>>>(a_gate, a_up, ATgu);
    adt_kernel<<<128, 256, 0, stream>>>(a_down, AdT);

    gemm_bt<64, 128><<<dim3(FDIM / 128, T_TOK / 64), 256, 0, stream>>>(XB, WgT, G, T_TOK, FDIM, HDIM);
    gemm_bt<64, 128><<<dim3(FDIM / 128, T_TOK / 64), 256, 0, stream>>>(XB, WuT, U, T_TOK, FDIM, HDIM);
    gemm_bt<64, 64><<<dim3(256 / 64, T_TOK / 64), 256, 0, stream>>>(XB, ATgu, XA, T_TOK, 256, HDIM);

    act2_kernel<<<dim3(NEXP, FDIM / 256, NCHUNK), 256, 0, stream>>>(
        G, U, XA, b_gate, b_up, CNT, LIST, ACT);

    gemm_bt<64, 64><<<dim3(HDIM / 64, 2 * T_TOK / 64), 256, 0, stream>>>((const ushort*)ACT, WdT, DOWN, 2 * T_TOK, HDIM, FDIM);
    gemm_bt<64, 64><<<dim3(128 / 64, 2 * T_TOK / 64), 256, 0, stream>>>((const ushort*)ACT, AdT, AD, 2 * T_TOK, 128, FDIM);

    combine2_kernel<<<T_TOK, 256, 0, stream>>>(DOWN, AD, b_down, SEL, WTS, out);
}

// Round 6
// 211.475 us; speedup vs baseline: 2.6908x; 1.3989x over previous
//
#include <hip/hip_runtime.h>
#include <hip/hip_bf16.h>

typedef __hip_bfloat16 bf16;
typedef __attribute__((ext_vector_type(4))) float f32x4;
typedef __attribute__((ext_vector_type(8))) __bf16 bf16x8;

#define T_TOK 1024
#define HDIM 1024
#define FDIM 4096
#define NEXP 8
#define RLORA 16
#define LSCALE 2.0f
#define N1 8448   // cols of fused GEMM1: 4096 gate + 4096 up + 256 XA
#define N2 1152   // cols of fused GEMM2: 1024 down + 128 AD

__device__ inline float b2f(bf16 v) { return __bfloat162float(v); }
__device__ inline bf16 f2b(float v) { return __float2bfloat16(v); }
__device__ inline ushort f2u(float v) { return __builtin_bit_cast(ushort, __float2bfloat16(v)); }
__device__ inline float u2f(ushort v) { return __bfloat162float(__builtin_bit_cast(bf16, v)); }

typedef const __attribute__((address_space(1))) unsigned int* gptr_t;
typedef __attribute__((address_space(3))) unsigned int* lptr_t;
__device__ __forceinline__ void glds16(const void* g, void* l) {
    __builtin_amdgcn_global_load_lds((gptr_t)g, (lptr_t)l, 16, 0, 0);
}

// ---------------- fp32 -> bf16 convert (x) ----------------
__global__ __launch_bounds__(256) void convert_kernel(
    const float* __restrict__ in, ushort* __restrict__ out, int n)
{
    int i = blockIdx.x * 256 + threadIdx.x;
    if (i * 4 < n) {
        const float4 v = *reinterpret_cast<const float4*>(in + i * 4);
        ushort4 o;
        o.x = f2u(v.x); o.y = f2u(v.y); o.z = f2u(v.z); o.w = f2u(v.w);
        *reinterpret_cast<ushort4*>(out + i * 4) = o;
    }
}

// ---------------- Router: logits, noisy logits, softmax+top2 (all fp32) -----
__global__ __launch_bounds__(256) void router_kernel(
    const float* __restrict__ x, const float* __restrict__ noise,
    const float* __restrict__ w_route, const float* __restrict__ w_noise,
    float* __restrict__ rl_out, int* __restrict__ SEL, float* __restrict__ WTS)
{
    const int t = blockIdx.x, tid = threadIdx.x;
    const float* xr = x + t * HDIM;
    float acc[16];
#pragma unroll
    for (int j = 0; j < 16; j++) acc[j] = 0.f;
    for (int h = tid; h < HDIM; h += 256) {
        float xv = xr[h];
        const float* wr = w_route + h * NEXP;
        const float* wn = w_noise + h * NEXP;
#pragma unroll
        for (int j = 0; j < 8; j++) acc[j] += xv * wr[j];
#pragma unroll
        for (int j = 0; j < 8; j++) acc[8 + j] += xv * wn[j];
    }
#pragma unroll
    for (int j = 0; j < 16; j++) {
        for (int off = 32; off > 0; off >>= 1) acc[j] += __shfl_down(acc[j], off, 64);
    }
    __shared__ float red[4][16];
    const int wave = tid >> 6, lane = tid & 63;
    if (lane == 0) {
#pragma unroll
        for (int j = 0; j < 16; j++) red[wave][j] = acc[j];
    }
    __syncthreads();
    if (tid == 0) {
        float rl[8];
#pragma unroll
        for (int j = 0; j < 8; j++) {
            float lg = red[0][j] + red[1][j] + red[2][j] + red[3][j];
            float nl = red[0][8 + j] + red[1][8 + j] + red[2][8 + j] + red[3][8 + j];
            float sp = fmaxf(nl, 0.f) + log1pf(expf(-fabsf(nl)));
            rl[j] = lg + noise[t * NEXP + j] * sp;
            rl_out[t * NEXP + j] = rl[j];
        }
        float m = rl[0];
#pragma unroll
        for (int j = 1; j < 8; j++) m = fmaxf(m, rl[j]);
        float p[8];
#pragma unroll
        for (int j = 0; j < 8; j++) p[j] = expf(rl[j] - m);
        int i1 = 0;
#pragma unroll
        for (int j = 1; j < 8; j++) if (p[j] > p[i1]) i1 = j;
        int i2 = (i1 == 0) ? 1 : 0;
#pragma unroll
        for (int j = 0; j < 8; j++) { if (j != i1 && p[j] > p[i2]) i2 = j; }
        float w1 = p[i1] / (p[i1] + p[i2]);
        float w2 = p[i2] / (p[i1] + p[i2]);
        SEL[t * 2 + 0] = i1; SEL[t * 2 + 1] = i2;
        WTS[t * 2 + 0] = w1; WTS[t * 2 + 1] = w2;
    }
}

// ---------------- Build per-expert (token,slot) lists via atomics -----------
__global__ __launch_bounds__(256) void build_lists_kernel(
    const int* __restrict__ SEL, int* __restrict__ CNT, int* __restrict__ LIST)
{
    const int p = blockIdx.x * 256 + threadIdx.x;  // 0..2047
    const int e = SEL[p];
    const int idx = atomicAdd(&CNT[e], 1);
    LIST[e * 2048 + idx] = p;
}

// -------- Transpose + convert: fp32 [rows,cols] -> bf16 [cols,rows] ---------
__global__ __launch_bounds__(256) void transpose_kernel(
    const float* __restrict__ in, ushort* __restrict__ out, int rows, int cols)
{
    __shared__ float tile[32][33];
    const int bx = blockIdx.x * 32;  // col base
    const int by = blockIdx.y * 32;  // row base
    const int tx = threadIdx.x & 31, ty = threadIdx.x >> 5;  // 32 x 8
#pragma unroll
    for (int i = 0; i < 32; i += 8)
        tile[ty + i][tx] = in[(size_t)(by + ty + i) * cols + bx + tx];
    __syncthreads();
#pragma unroll
    for (int i = 0; i < 32; i += 8)
        out[(size_t)(bx + ty + i) * rows + by + tx] = f2u(tile[tx][ty + i]);
}

// -------- Pack LoRA-A (gate/up) into AT[256][H] bf16, row = e*32+mat*16+r ---
__global__ __launch_bounds__(256) void at_gu_kernel(
    const float* __restrict__ a_gate, const float* __restrict__ a_up,
    ushort* __restrict__ AT)
{
    const int row = blockIdx.x;  // 0..255
    const int e = row >> 5, mat = (row >> 4) & 1, r = row & 15;
    const float* src = (mat ? a_up : a_gate) + (size_t)e * HDIM * RLORA;
    for (int h = threadIdx.x; h < HDIM; h += 256)
        AT[(size_t)row * HDIM + h] = f2u(src[h * RLORA + r]);
}

// -------- Pack a_down into AdT[128][F] bf16, row = e*16+r -------------------
__global__ __launch_bounds__(256) void adt_kernel(
    const float* __restrict__ a_down, ushort* __restrict__ AdT)
{
    const int row = blockIdx.x;  // 0..127
    const int e = row >> 4, r = row & 15;
    const float* src = a_down + (size_t)e * FDIM * RLORA;
    for (int f = threadIdx.x; f < FDIM; f += 256)
        AdT[(size_t)row * FDIM + f] = f2u(src[f * RLORA + r]);
}

// ---- m97-style MFMA GEMM: C[M,N] = A[M,K] * Bt[N,K]^T, 128x128, BK=64 ------
// glds width-16 staging with both-sides XOR swizzle (T2/m201 pattern).
template <bool OUT_BF16>
__global__ __launch_bounds__(256) void gemm128(
    const ushort* __restrict__ A, const ushort* __restrict__ Bt,
    void* __restrict__ Cv, int M, int N, int Kd)
{
    __shared__ __align__(16) ushort sA[128 * 64];
    __shared__ __align__(16) ushort sB[128 * 64];
    const int tid = threadIdx.x;
    const int wave = tid >> 6, lane = tid & 63;
    const int wm = wave >> 1, wn = wave & 1;   // 2x2 waves; wave tile 64x64
    const int bm0 = blockIdx.y * 128, bn0 = blockIdx.x * 128;

    f32x4 acc[4][4];
#pragma unroll
    for (int m = 0; m < 4; m++)
#pragma unroll
        for (int n = 0; n < 4; n++) acc[m][n] = (f32x4){0.f, 0.f, 0.f, 0.f};

    // Per-pass staging: idx = i*256+tid; row = idx>>3; swizzled src group = (idx&7)^(row&7).
    const int srow = tid >> 3;                       // 0..31 within pass
    const int sgrp8 = ((tid & 7) ^ (srow & 7)) * 8;  // pre-swizzled global col (elems)

    for (int k0 = 0; k0 < Kd; k0 += 64) {
#pragma unroll
        for (int i = 0; i < 4; i++) {
            const int row = i * 32 + srow;
            glds16(A + (size_t)(bm0 + row) * Kd + k0 + sgrp8, &sA[i * 2048 + wave * 512]);
            glds16(Bt + (size_t)(bn0 + row) * Kd + k0 + sgrp8, &sB[i * 2048 + wave * 512]);
        }
        __syncthreads();  // drains vmcnt -> LDS tile complete
#pragma unroll
        for (int kk = 0; kk < 2; kk++) {
            bf16x8 af[4], bfr[4];
            const int colb = (kk * 32 + (lane >> 4) * 8) * 2;  // byte col
#pragma unroll
            for (int m = 0; m < 4; m++) {
                const int row = wm * 64 + m * 16 + (lane & 15);
                af[m] = *reinterpret_cast<const bf16x8*>(
                    (const char*)sA + row * 128 + (colb ^ ((row & 7) << 4)));
            }
#pragma unroll
            for (int n = 0; n < 4; n++) {
                const int row = wn * 64 + n * 16 + (lane & 15);
                bfr[n] = *reinterpret_cast<const bf16x8*>(
                    (const char*)sB + row * 128 + (colb ^ ((row & 7) << 4)));
            }
#pragma unroll
            for (int m = 0; m < 4; m++)
#pragma unroll
                for (int n = 0; n < 4; n++)
                    acc[m][n] = __builtin_amdgcn_mfma_f32_16x16x32_bf16(af[m], bfr[n], acc[m][n], 0, 0, 0);
        }
        __syncthreads();  // compute done before next overwrite
    }

    const int rg = lane & 15, qg = lane >> 4;
#pragma unroll
    for (int m = 0; m < 4; m++) {
#pragma unroll
        for (int n = 0; n < 4; n++) {
            const int row0 = bm0 + wm * 64 + m * 16 + qg * 4;
            const int col = bn0 + wn * 64 + n * 16 + rg;
#pragma unroll
            for (int j = 0; j < 4; j++) {
                if (OUT_BF16)
                    ((ushort*)Cv)[(size_t)(row0 + j) * N + col] = f2u(acc[m][n][j]);
                else
                    ((float*)Cv)[(size_t)(row0 + j) * N + col] = acc[m][n][j];
            }
        }
    }
}

// -------- Expert-grouped LoRA gate/up + SiLU epilogue -> ACT ----------------
// grid (NEXP, FDIM/256, NCHUNK); block 256; B tiles staged in LDS once/block.
#define NCHUNK 8
__global__ __launch_bounds__(256) void act2_kernel(
    const ushort* __restrict__ GU,   // [T, N1] bf16: G | U | XA
    const float* __restrict__ b_gate, const float* __restrict__ b_up,
    const int* __restrict__ CNT, const int* __restrict__ LIST,
    bf16* __restrict__ ACT)
{
    const int e = blockIdx.x, f0 = blockIdx.y * 256, chunk = blockIdx.z;
    const int tid = threadIdx.x;
    __shared__ float sBg[16][256];
    __shared__ float sBu[16][256];
    __shared__ float xa_s[2][32];

    const float* bg = b_gate + (size_t)e * RLORA * FDIM + f0;
    const float* bu = b_up + (size_t)e * RLORA * FDIM + f0;
#pragma unroll
    for (int r = 0; r < 16; r++) {
        sBg[r][tid] = bg[(size_t)r * FDIM + tid];
        sBu[r][tid] = bu[(size_t)r * FDIM + tid];
    }
    __syncthreads();

    const int n = CNT[e];
    int j = 0;
    for (int i = chunk; i < n; i += NCHUNK, ++j) {
        const int p = LIST[e * 2048 + i];
        const int t = p >> 1;
        const int buf = j & 1;
        if (tid < 32) xa_s[buf][tid] = u2f(GU[(size_t)t * N1 + 8192 + e * 32 + tid]);
        __syncthreads();
        const float g = u2f(GU[(size_t)t * N1 + f0 + tid]);
        const float u = u2f(GU[(size_t)t * N1 + 4096 + f0 + tid]);
        float lg = 0.f, lu = 0.f;
#pragma unroll
        for (int r = 0; r < 16; r++) {
            lg += xa_s[buf][r] * sBg[r][tid];
            lu += xa_s[buf][16 + r] * sBu[r][tid];
        }
        const float gate = g + LSCALE * lg;
        const float up = u + LSCALE * lu;
        ACT[(size_t)p * FDIM + f0 + tid] = f2b((gate / (1.f + expf(-gate))) * up);
    }
}

// -------- Combine: out[t] = sum_k wk*(DOWN[p] + 2*AD[p]·b_down[e_k]) --------
__global__ __launch_bounds__(256) void combine2_kernel(
    const float* __restrict__ C2,    // [2048, N2]: DOWN | AD
    const float* __restrict__ b_down, const int* __restrict__ SEL,
    const float* __restrict__ WTS, float* __restrict__ out)
{
    const int t = blockIdx.x, tid = threadIdx.x;
    const int e0 = SEL[t * 2 + 0], e1 = SEL[t * 2 + 1];
    const float w0 = WTS[t * 2 + 0], w1 = WTS[t * 2 + 1];
    __shared__ float ad0[16], ad1[16];
    if (tid < 16) ad0[tid] = C2[(size_t)(2 * t) * N2 + 1024 + e0 * 16 + tid];
    else if (tid < 32) ad1[tid - 16] = C2[(size_t)(2 * t + 1) * N2 + 1024 + e1 * 16 + (tid - 16)];
    __syncthreads();
    const float* B0 = b_down + (size_t)e0 * RLORA * HDIM;
    const float* B1 = b_down + (size_t)e1 * RLORA * HDIM;
    for (int h = tid; h < HDIM; h += 256) {
        float v0 = C2[(size_t)(2 * t) * N2 + h];
        float v1 = C2[(size_t)(2 * t + 1) * N2 + h];
        float l0 = 0.f, l1 = 0.f;
#pragma unroll
        for (int r = 0; r < 16; r++) {
            l0 += ad0[r] * B0[r * HDIM + h];
            l1 += ad1[r] * B1[r * HDIM + h];
        }
        out[(size_t)t * HDIM + h] = w0 * (v0 + LSCALE * l0) + w1 * (v1 + LSCALE * l1);
    }
}

extern "C" void kernel_launch(void* const* d_in, const int* in_sizes, int n_in,
                              void* d_out, int out_size, void* d_ws, size_t ws_size,
                              hipStream_t stream) {
    (void)in_sizes; (void)n_in; (void)out_size; (void)ws_size;
    const float* x       = (const float*)d_in[0];
    const float* noise   = (const float*)d_in[1];
    const float* w_route = (const float*)d_in[2];
    const float* w_noise = (const float*)d_in[3];
    const float* w_gate  = (const float*)d_in[4];
    const float* w_up    = (const float*)d_in[5];
    const float* w_down  = (const float*)d_in[6];
    const float* a_gate  = (const float*)d_in[7];
    const float* b_gate  = (const float*)d_in[8];
    const float* a_up    = (const float*)d_in[9];
    const float* b_up    = (const float*)d_in[10];
    const float* a_down  = (const float*)d_in[11];
    const float* b_down  = (const float*)d_in[12];
    float* out    = (float*)d_out;
    float* rl_out = out + (size_t)T_TOK * HDIM;

    char* ws = (char*)d_ws;
    ushort* C1b  = (ushort*)(ws);                         // [1024][8448] bf16 = 16.5 MB
    ushort* WGUA = (ushort*)(ws + (size_t)(18 << 20));    // [8448][1024] bf16 = 16.5 MB
    bf16*   ACT  = (bf16*)(ws + (size_t)(36 << 20));      // [2048][4096] bf16 = 16 MB
    ushort* WDA  = (ushort*)(ws + (size_t)(52 << 20));    // [1152][4096] bf16 = 9 MB
    float*  C2   = (float*)(ws + (size_t)(62 << 20));     // [2048][1152] fp32 = 9 MB
    ushort* XB   = (ushort*)(ws + (size_t)(72 << 20));    // [1024][1024] bf16 = 2 MB
    int*    LIST = (int*)(ws + (size_t)(75 << 20));       // 64 KB
    int*    CNT  = (int*)(ws + (size_t)(75 << 20) + (1 << 17));
    int*    SEL  = (int*)(ws + (size_t)(75 << 20) + (1 << 17) + 4096);
    float*  WTS  = (float*)(ws + (size_t)(75 << 20) + (1 << 17) + 16384);

    hipMemsetAsync(CNT, 0, NEXP * sizeof(int), stream);

    router_kernel<<<T_TOK, 256, 0, stream>>>(x, noise, w_route, w_noise, rl_out, SEL, WTS);
    build_lists_kernel<<<2 * T_TOK / 256, 256, 0, stream>>>(SEL, CNT, LIST);

    convert_kernel<<<(T_TOK * HDIM / 4 + 255) / 256, 256, 0, stream>>>(x, XB, T_TOK * HDIM);

    // WGUA rows: [0,4096) = w_gate^T, [4096,8192) = w_up^T, [8192,8448) = LoRA-A pack
    transpose_kernel<<<dim3(FDIM / 32, HDIM / 32), 256, 0, stream>>>(w_gate, WGUA, HDIM, FDIM);
    transpose_kernel<<<dim3(FDIM / 32, HDIM / 32), 256, 0, stream>>>(w_up, WGUA + (size_t)4096 * HDIM, HDIM, FDIM);
    at_gu_kernel<<<256, 256, 0, stream>>>(a_gate, a_up, WGUA + (size_t)8192 * HDIM);
    // WDA rows: [0,1024) = w_down^T, [1024,1152) = a_down pack
    transpose_kernel<<<dim3(HDIM / 32, FDIM / 32), 256, 0, stream>>>(w_down, WDA, FDIM, HDIM);
    adt_kernel<<<128, 256, 0, stream>>>(a_down, WDA + (size_t)1024 * FDIM);

    // GEMM1: C1b[1024][8448] = XB @ WGUA^T  (bf16 out)
    gemm128<true><<<dim3(N1 / 128, T_TOK / 128), 256, 0, stream>>>(XB, WGUA, C1b, T_TOK, N1, HDIM);

    act2_kernel<<<dim3(NEXP, FDIM / 256, NCHUNK), 256, 0, stream>>>(
        C1b, b_gate, b_up, CNT, LIST, ACT);

    // GEMM2: C2[2048][1152] = ACT @ WDA^T  (fp32 out)
    gemm128<false><<<dim3(N2 / 128, 2 * T_TOK / 128), 256, 0, stream>>>(
        (const ushort*)ACT, WDA, C2, 2 * T_TOK, N2, FDIM);

    combine2_kernel<<<T_TOK, 256, 0, stream>>>(C2, b_down, SEL, WTS, out);
}

// Round 7
// 186.460 us; speedup vs baseline: 3.0519x; 1.1342x over previous
//
#include <hip/hip_runtime.h>
#include <hip/hip_bf16.h>

typedef __hip_bfloat16 bf16;
typedef __attribute__((ext_vector_type(4))) float f32x4;
typedef __attribute__((ext_vector_type(8))) __bf16 bf16x8;

#define T_TOK 1024
#define HDIM 1024
#define FDIM 4096
#define NEXP 8
#define RLORA 16
#define LSCALE 2.0f
#define N1 8448   // cols of fused GEMM1: 4096 gate + 4096 up + 256 XA
#define N2 1152   // cols of fused GEMM2: 1024 down + 128 AD
#define SPLITK2 4

__device__ inline float b2f(bf16 v) { return __bfloat162float(v); }
__device__ inline bf16 f2b(float v) { return __float2bfloat16(v); }
__device__ inline ushort f2u(float v) { return __builtin_bit_cast(ushort, __float2bfloat16(v)); }
__device__ inline float u2f(ushort v) { return __bfloat162float(__builtin_bit_cast(bf16, v)); }

typedef const __attribute__((address_space(1))) unsigned int* gptr_t;
typedef __attribute__((address_space(3))) unsigned int* lptr_t;
__device__ __forceinline__ void glds16(const void* g, void* l) {
    __builtin_amdgcn_global_load_lds((gptr_t)g, (lptr_t)l, 16, 0, 0);
}

// ---------------- Router + top2 + expert list build (fused) -----------------
__global__ __launch_bounds__(256) void router_kernel(
    const float* __restrict__ x, const float* __restrict__ noise,
    const float* __restrict__ w_route, const float* __restrict__ w_noise,
    float* __restrict__ rl_out, int* __restrict__ SEL, float* __restrict__ WTS,
    int* __restrict__ CNT, int* __restrict__ LIST)
{
    const int t = blockIdx.x, tid = threadIdx.x;
    const float* xr = x + t * HDIM;
    float acc[16];
#pragma unroll
    for (int j = 0; j < 16; j++) acc[j] = 0.f;
    for (int h = tid; h < HDIM; h += 256) {
        float xv = xr[h];
        const float* wr = w_route + h * NEXP;
        const float* wn = w_noise + h * NEXP;
#pragma unroll
        for (int j = 0; j < 8; j++) acc[j] += xv * wr[j];
#pragma unroll
        for (int j = 0; j < 8; j++) acc[8 + j] += xv * wn[j];
    }
#pragma unroll
    for (int j = 0; j < 16; j++) {
        for (int off = 32; off > 0; off >>= 1) acc[j] += __shfl_down(acc[j], off, 64);
    }
    __shared__ float red[4][16];
    const int wave = tid >> 6, lane = tid & 63;
    if (lane == 0) {
#pragma unroll
        for (int j = 0; j < 16; j++) red[wave][j] = acc[j];
    }
    __syncthreads();
    if (tid == 0) {
        float rl[8];
#pragma unroll
        for (int j = 0; j < 8; j++) {
            float lg = red[0][j] + red[1][j] + red[2][j] + red[3][j];
            float nl = red[0][8 + j] + red[1][8 + j] + red[2][8 + j] + red[3][8 + j];
            float sp = fmaxf(nl, 0.f) + log1pf(expf(-fabsf(nl)));
            rl[j] = lg + noise[t * NEXP + j] * sp;
            rl_out[t * NEXP + j] = rl[j];
        }
        float m = rl[0];
#pragma unroll
        for (int j = 1; j < 8; j++) m = fmaxf(m, rl[j]);
        float p[8];
#pragma unroll
        for (int j = 0; j < 8; j++) p[j] = expf(rl[j] - m);
        int i1 = 0;
#pragma unroll
        for (int j = 1; j < 8; j++) if (p[j] > p[i1]) i1 = j;
        int i2 = (i1 == 0) ? 1 : 0;
#pragma unroll
        for (int j = 0; j < 8; j++) { if (j != i1 && p[j] > p[i2]) i2 = j; }
        float w1 = p[i1] / (p[i1] + p[i2]);
        float w2 = p[i2] / (p[i1] + p[i2]);
        SEL[t * 2 + 0] = i1; SEL[t * 2 + 1] = i2;
        WTS[t * 2 + 0] = w1; WTS[t * 2 + 1] = w2;
        int idx0 = atomicAdd(&CNT[i1], 1); LIST[i1 * 2048 + idx0] = 2 * t;
        int idx1 = atomicAdd(&CNT[i2], 1); LIST[i2 * 2048 + idx1] = 2 * t + 1;
    }
}

// ---------------- Fused prep: 3 transposes + 2 LoRA-A packs + x convert -----
// blocks: [0,4096) w_gate T; [4096,8192) w_up T; [8192,12288) w_down T;
//         [12288,12544) at_gu; [12544,12672) adt; [12672,13696) convert x
__device__ __forceinline__ void transpose_tile(
    const float* __restrict__ in, ushort* __restrict__ out,
    int rows, int cols, int bx, int by, int tid)
{
    __shared__ float tile[32][33];
    const int tx = tid & 31, ty = tid >> 5;
#pragma unroll
    for (int i = 0; i < 32; i += 8)
        tile[ty + i][tx] = in[(size_t)(by + ty + i) * cols + bx + tx];
    __syncthreads();
#pragma unroll
    for (int i = 0; i < 32; i += 8)
        out[(size_t)(bx + ty + i) * rows + by + tx] = f2u(tile[tx][ty + i]);
}

__global__ __launch_bounds__(256) void prep_kernel(
    const float* __restrict__ x,
    const float* __restrict__ w_gate, const float* __restrict__ w_up,
    const float* __restrict__ w_down,
    const float* __restrict__ a_gate, const float* __restrict__ a_up,
    const float* __restrict__ a_down,
    ushort* __restrict__ XB, ushort* __restrict__ WGUA, ushort* __restrict__ WDA)
{
    const int bid = blockIdx.x, tid = threadIdx.x;
    if (bid < 4096) {
        transpose_tile(w_gate, WGUA, HDIM, FDIM, (bid & 127) * 32, (bid >> 7) * 32, tid);
    } else if (bid < 8192) {
        const int s = bid - 4096;
        transpose_tile(w_up, WGUA + (size_t)4096 * HDIM, HDIM, FDIM, (s & 127) * 32, (s >> 7) * 32, tid);
    } else if (bid < 12288) {
        const int s = bid - 8192;
        transpose_tile(w_down, WDA, FDIM, HDIM, (s & 31) * 32, (s >> 5) * 32, tid);
    } else if (bid < 12544) {
        const int row = bid - 12288;  // 0..255: e*32 + mat*16 + r
        const int e = row >> 5, mat = (row >> 4) & 1, r = row & 15;
        const float* src = (mat ? a_up : a_gate) + (size_t)e * HDIM * RLORA;
        ushort* dst = WGUA + (size_t)(8192 + row) * HDIM;
        for (int h = tid; h < HDIM; h += 256) dst[h] = f2u(src[h * RLORA + r]);
    } else if (bid < 12672) {
        const int row = bid - 12544;  // 0..127: e*16 + r
        const int e = row >> 4, r = row & 15;
        const float* src = a_down + (size_t)e * FDIM * RLORA;
        ushort* dst = WDA + (size_t)(1024 + row) * FDIM;
        for (int f = tid; f < FDIM; f += 256) dst[f] = f2u(src[f * RLORA + r]);
    } else {
        const int i = (bid - 12672) * 256 + tid;
        const float4 v = *reinterpret_cast<const float4*>(x + (size_t)i * 4);
        ushort4 o;
        o.x = f2u(v.x); o.y = f2u(v.y); o.z = f2u(v.z); o.w = f2u(v.w);
        *reinterpret_cast<ushort4*>(XB + (size_t)i * 4) = o;
    }
}

// ---- m97-style MFMA GEMM: 128x128 tile, BK=64, glds + XOR swizzle ----------
// Linear grid.x (col-major: id = x*ny + y) with XCD-chunked bijective swizzle;
// grid.z = split-K chunk, partials at Cv + z*M*N.
template <bool OUT_BF16, int SPLITK>
__global__ __launch_bounds__(256) void gemm128(
    const ushort* __restrict__ A, const ushort* __restrict__ Bt,
    void* __restrict__ Cv, int M, int N, int Kd, int ny)
{
    __shared__ __align__(16) ushort sA[128 * 64];
    __shared__ __align__(16) ushort sB[128 * 64];
    const int nwg = gridDim.x;
    const int q = nwg >> 3;  // nwg % 8 == 0 required
    const int wg = (blockIdx.x & 7) * q + (blockIdx.x >> 3);
    const int bn0 = (wg / ny) * 128, bm0 = (wg % ny) * 128;

    const int tid = threadIdx.x;
    const int wave = tid >> 6, lane = tid & 63;
    const int wm = wave >> 1, wn = wave & 1;

    f32x4 acc[4][4];
#pragma unroll
    for (int m = 0; m < 4; m++)
#pragma unroll
        for (int n = 0; n < 4; n++) acc[m][n] = (f32x4){0.f, 0.f, 0.f, 0.f};

    const int srow = tid >> 3;                       // 0..31 per pass
    const int sgrp8 = ((tid & 7) ^ (srow & 7)) * 8;  // pre-swizzled col (elems)

    const int kchunk = Kd / SPLITK;
    const int kbeg = blockIdx.z * kchunk, kend = kbeg + kchunk;
    for (int k0 = kbeg; k0 < kend; k0 += 64) {
#pragma unroll
        for (int i = 0; i < 4; i++) {
            const int row = i * 32 + srow;
            glds16(A + (size_t)(bm0 + row) * Kd + k0 + sgrp8, &sA[i * 2048 + wave * 512]);
            glds16(Bt + (size_t)(bn0 + row) * Kd + k0 + sgrp8, &sB[i * 2048 + wave * 512]);
        }
        __syncthreads();
#pragma unroll
        for (int kk = 0; kk < 2; kk++) {
            bf16x8 af[4], bfr[4];
            const int colb = (kk * 32 + (lane >> 4) * 8) * 2;
#pragma unroll
            for (int m = 0; m < 4; m++) {
                const int row = wm * 64 + m * 16 + (lane & 15);
                af[m] = *reinterpret_cast<const bf16x8*>(
                    (const char*)sA + row * 128 + (colb ^ ((row & 7) << 4)));
            }
#pragma unroll
            for (int n = 0; n < 4; n++) {
                const int row = wn * 64 + n * 16 + (lane & 15);
                bfr[n] = *reinterpret_cast<const bf16x8*>(
                    (const char*)sB + row * 128 + (colb ^ ((row & 7) << 4)));
            }
#pragma unroll
            for (int m = 0; m < 4; m++)
#pragma unroll
                for (int n = 0; n < 4; n++)
                    acc[m][n] = __builtin_amdgcn_mfma_f32_16x16x32_bf16(af[m], bfr[n], acc[m][n], 0, 0, 0);
        }
        __syncthreads();
    }

    const size_t zoff = (size_t)blockIdx.z * M * N;
    const int rg = lane & 15, qg = lane >> 4;
#pragma unroll
    for (int m = 0; m < 4; m++) {
#pragma unroll
        for (int n = 0; n < 4; n++) {
            const int row0 = bm0 + wm * 64 + m * 16 + qg * 4;
            const int col = bn0 + wn * 64 + n * 16 + rg;
#pragma unroll
            for (int j = 0; j < 4; j++) {
                if (OUT_BF16)
                    ((ushort*)Cv)[zoff + (size_t)(row0 + j) * N + col] = f2u(acc[m][n][j]);
                else
                    ((float*)Cv)[zoff + (size_t)(row0 + j) * N + col] = acc[m][n][j];
            }
        }
    }
}

// -------- Expert-grouped LoRA gate/up + SiLU epilogue -> ACT ----------------
#define NCHUNK 8
__global__ __launch_bounds__(256) void act2_kernel(
    const ushort* __restrict__ GU,   // [T, N1] bf16: G | U | XA
    const float* __restrict__ b_gate, const float* __restrict__ b_up,
    const int* __restrict__ CNT, const int* __restrict__ LIST,
    bf16* __restrict__ ACT)
{
    const int e = blockIdx.x, f0 = blockIdx.y * 256, chunk = blockIdx.z;
    const int tid = threadIdx.x;
    __shared__ float sBg[16][256];
    __shared__ float sBu[16][256];
    __shared__ float xa_s[2][32];

    const float* bg = b_gate + (size_t)e * RLORA * FDIM + f0;
    const float* bu = b_up + (size_t)e * RLORA * FDIM + f0;
#pragma unroll
    for (int r = 0; r < 16; r++) {
        sBg[r][tid] = bg[(size_t)r * FDIM + tid];
        sBu[r][tid] = bu[(size_t)r * FDIM + tid];
    }
    __syncthreads();

    const int n = CNT[e];
    int j = 0;
    for (int i = chunk; i < n; i += NCHUNK, ++j) {
        const int p = LIST[e * 2048 + i];
        const int t = p >> 1;
        const int buf = j & 1;
        if (tid < 32) xa_s[buf][tid] = u2f(GU[(size_t)t * N1 + 8192 + e * 32 + tid]);
        __syncthreads();
        const float g = u2f(GU[(size_t)t * N1 + f0 + tid]);
        const float u = u2f(GU[(size_t)t * N1 + 4096 + f0 + tid]);
        float lg = 0.f, lu = 0.f;
#pragma unroll
        for (int r = 0; r < 16; r++) {
            lg += xa_s[buf][r] * sBg[r][tid];
            lu += xa_s[buf][16 + r] * sBu[r][tid];
        }
        const float gate = g + LSCALE * lg;
        const float up = u + LSCALE * lu;
        ACT[(size_t)p * FDIM + f0 + tid] = f2b((gate / (1.f + expf(-gate))) * up);
    }
}

// -------- Combine: split-K reduce + LoRA-down expand + weighted sum ---------
__global__ __launch_bounds__(256) void combine2_kernel(
    const float* __restrict__ C2,    // [SPLITK2][2048][N2]: DOWN | AD partials
    const float* __restrict__ b_down, const int* __restrict__ SEL,
    const float* __restrict__ WTS, float* __restrict__ out)
{
    const int t = blockIdx.x, tid = threadIdx.x;
    const int e0 = SEL[t * 2 + 0], e1 = SEL[t * 2 + 1];
    const float w0 = WTS[t * 2 + 0], w1 = WTS[t * 2 + 1];
    __shared__ float ad0[16], ad1[16];
    if (tid < 16) {
        float v = 0.f;
#pragma unroll
        for (int z = 0; z < SPLITK2; z++)
            v += C2[((size_t)z * 2048 + 2 * t) * N2 + 1024 + e0 * 16 + tid];
        ad0[tid] = v;
    } else if (tid < 32) {
        float v = 0.f;
#pragma unroll
        for (int z = 0; z < SPLITK2; z++)
            v += C2[((size_t)z * 2048 + 2 * t + 1) * N2 + 1024 + e1 * 16 + (tid - 16)];
        ad1[tid - 16] = v;
    }
    __syncthreads();
    const float* B0 = b_down + (size_t)e0 * RLORA * HDIM;
    const float* B1 = b_down + (size_t)e1 * RLORA * HDIM;
    for (int h = tid; h < HDIM; h += 256) {
        float v0 = 0.f, v1 = 0.f;
#pragma unroll
        for (int z = 0; z < SPLITK2; z++) {
            v0 += C2[((size_t)z * 2048 + 2 * t) * N2 + h];
            v1 += C2[((size_t)z * 2048 + 2 * t + 1) * N2 + h];
        }
        float l0 = 0.f, l1 = 0.f;
#pragma unroll
        for (int r = 0; r < 16; r++) {
            l0 += ad0[r] * B0[r * HDIM + h];
            l1 += ad1[r] * B1[r * HDIM + h];
        }
        out[(size_t)t * HDIM + h] = w0 * (v0 + LSCALE * l0) + w1 * (v1 + LSCALE * l1);
    }
}

extern "C" void kernel_launch(void* const* d_in, const int* in_sizes, int n_in,
                              void* d_out, int out_size, void* d_ws, size_t ws_size,
                              hipStream_t stream) {
    (void)in_sizes; (void)n_in; (void)out_size; (void)ws_size;
    const float* x       = (const float*)d_in[0];
    const float* noise   = (const float*)d_in[1];
    const float* w_route = (const float*)d_in[2];
    const float* w_noise = (const float*)d_in[3];
    const float* w_gate  = (const float*)d_in[4];
    const float* w_up    = (const float*)d_in[5];
    const float* w_down  = (const float*)d_in[6];
    const float* a_gate  = (const float*)d_in[7];
    const float* b_gate  = (const float*)d_in[8];
    const float* a_up    = (const float*)d_in[9];
    const float* b_up    = (const float*)d_in[10];
    const float* a_down  = (const float*)d_in[11];
    const float* b_down  = (const float*)d_in[12];
    float* out    = (float*)d_out;
    float* rl_out = out + (size_t)T_TOK * HDIM;

    char* ws = (char*)d_ws;
    float*  C2   = (float*)(ws);                          // [4][2048][1152] fp32 = 36 MB (reuses WGUA space later)
    ushort* WGUA = (ushort*)(ws + (size_t)(18 << 20));    // [8448][1024] bf16 = 16.5 MB (dead after GEMM1; C2 overlaps OK since C2 written after)
    bf16*   ACT  = (bf16*)(ws + (size_t)(36 << 20));      // [2048][4096] bf16 = 16 MB
    ushort* WDA  = (ushort*)(ws + (size_t)(52 << 20));    // [1152][4096] bf16 = 9 MB
    ushort* XB   = (ushort*)(ws + (size_t)(62 << 20));    // [1024][1024] bf16 = 2 MB
    ushort* C1b  = (ushort*)(ws + (size_t)(64 << 20));    // [1024][8448] bf16 = 16.5 MB
    int*    LIST = (int*)(ws + (size_t)(81 << 20));       // 64 KB
    int*    CNT  = (int*)(ws + (size_t)(81 << 20) + (1 << 17));
    int*    SEL  = (int*)(ws + (size_t)(81 << 20) + (1 << 17) + 4096);
    float*  WTS  = (float*)(ws + (size_t)(81 << 20) + (1 << 17) + 16384);

    hipMemsetAsync(CNT, 0, NEXP * sizeof(int), stream);

    router_kernel<<<T_TOK, 256, 0, stream>>>(x, noise, w_route, w_noise, rl_out, SEL, WTS, CNT, LIST);

    prep_kernel<<<13696, 256, 0, stream>>>(x, w_gate, w_up, w_down, a_gate, a_up, a_down,
                                           XB, WGUA, WDA);

    // GEMM1: C1b[1024][8448] = XB @ WGUA^T  (bf16 out). grid 66*8=528 (%8==0)
    gemm128<true, 1><<<dim3((N1 / 128) * (T_TOK / 128), 1, 1), 256, 0, stream>>>(
        XB, WGUA, C1b, T_TOK, N1, HDIM, T_TOK / 128);

    act2_kernel<<<dim3(NEXP, FDIM / 256, NCHUNK), 256, 0, stream>>>(
        C1b, b_gate, b_up, CNT, LIST, ACT);

    // GEMM2: C2[z][2048][1152] = ACT @ WDA^T partials. grid 9*16=144 (%8==0), z=4
    gemm128<false, SPLITK2><<<dim3((N2 / 128) * (2 * T_TOK / 128), 1, SPLITK2), 256, 0, stream>>>(
        (const ushort*)ACT, WDA, C2, 2 * T_TOK, N2, FDIM, 2 * T_TOK / 128);

    combine2_kernel<<<T_TOK, 256, 0, stream>>>(C2, b_down, SEL, WTS, out);
}

// Round 8
// 170.085 us; speedup vs baseline: 3.3457x; 1.0963x over previous
//
#include <hip/hip_runtime.h>
#include <hip/hip_bf16.h>

typedef __hip_bfloat16 bf16;
typedef __attribute__((ext_vector_type(4))) float f32x4;
typedef __attribute__((ext_vector_type(8))) __bf16 bf16x8;

#define T_TOK 1024
#define HDIM 1024
#define FDIM 4096
#define NEXP 8
#define RLORA 16
#define LSCALE 2.0f
#define N1 8448   // cols of fused GEMM1: 4096 gate + 4096 up + 256 XA
#define N2 1152   // cols of fused GEMM2: 1024 down + 128 AD
#define SPLITK2 4
#define ACT_NCHUNK 8

__device__ inline float b2f(bf16 v) { return __bfloat162float(v); }
__device__ inline bf16 f2b(float v) { return __float2bfloat16(v); }
__device__ inline ushort f2u(float v) { return __builtin_bit_cast(ushort, __float2bfloat16(v)); }
__device__ inline float u2f(ushort v) { return __bfloat162float(__builtin_bit_cast(bf16, v)); }
__device__ inline float lo2f(unsigned w) { return __builtin_bit_cast(float, w << 16); }
__device__ inline float hi2f(unsigned w) { return __builtin_bit_cast(float, w & 0xffff0000u); }

typedef const __attribute__((address_space(1))) unsigned int* gptr_t;
typedef __attribute__((address_space(3))) unsigned int* lptr_t;
__device__ __forceinline__ void glds16(const void* g, void* l) {
    __builtin_amdgcn_global_load_lds((gptr_t)g, (lptr_t)l, 16, 0, 0);
}

// ---------------- Router + top2 + expert list build (fused) -----------------
__global__ __launch_bounds__(256) void router_kernel(
    const float* __restrict__ x, const float* __restrict__ noise,
    const float* __restrict__ w_route, const float* __restrict__ w_noise,
    float* __restrict__ rl_out, int* __restrict__ SEL, float* __restrict__ WTS,
    int* __restrict__ CNT, int* __restrict__ LIST)
{
    const int t = blockIdx.x, tid = threadIdx.x;
    const float* xr = x + t * HDIM;
    float acc[16];
#pragma unroll
    for (int j = 0; j < 16; j++) acc[j] = 0.f;
    for (int h = tid; h < HDIM; h += 256) {
        float xv = xr[h];
        const float* wr = w_route + h * NEXP;
        const float* wn = w_noise + h * NEXP;
#pragma unroll
        for (int j = 0; j < 8; j++) acc[j] += xv * wr[j];
#pragma unroll
        for (int j = 0; j < 8; j++) acc[8 + j] += xv * wn[j];
    }
#pragma unroll
    for (int j = 0; j < 16; j++) {
        for (int off = 32; off > 0; off >>= 1) acc[j] += __shfl_down(acc[j], off, 64);
    }
    __shared__ float red[4][16];
    const int wave = tid >> 6, lane = tid & 63;
    if (lane == 0) {
#pragma unroll
        for (int j = 0; j < 16; j++) red[wave][j] = acc[j];
    }
    __syncthreads();
    if (tid == 0) {
        float rl[8];
#pragma unroll
        for (int j = 0; j < 8; j++) {
            float lg = red[0][j] + red[1][j] + red[2][j] + red[3][j];
            float nl = red[0][8 + j] + red[1][8 + j] + red[2][8 + j] + red[3][8 + j];
            float sp = fmaxf(nl, 0.f) + log1pf(expf(-fabsf(nl)));
            rl[j] = lg + noise[t * NEXP + j] * sp;
            rl_out[t * NEXP + j] = rl[j];
        }
        float m = rl[0];
#pragma unroll
        for (int j = 1; j < 8; j++) m = fmaxf(m, rl[j]);
        float p[8];
#pragma unroll
        for (int j = 0; j < 8; j++) p[j] = expf(rl[j] - m);
        int i1 = 0;
#pragma unroll
        for (int j = 1; j < 8; j++) if (p[j] > p[i1]) i1 = j;
        int i2 = (i1 == 0) ? 1 : 0;
#pragma unroll
        for (int j = 0; j < 8; j++) { if (j != i1 && p[j] > p[i2]) i2 = j; }
        float w1 = p[i1] / (p[i1] + p[i2]);
        float w2 = p[i2] / (p[i1] + p[i2]);
        SEL[t * 2 + 0] = i1; SEL[t * 2 + 1] = i2;
        WTS[t * 2 + 0] = w1; WTS[t * 2 + 1] = w2;
        int idx0 = atomicAdd(&CNT[i1], 1); LIST[i1 * 2048 + idx0] = 2 * t;
        int idx1 = atomicAdd(&CNT[i2], 1); LIST[i2 * 2048 + idx1] = 2 * t + 1;
    }
}

// ---------------- Fused prep: 3 transposes + 2 LoRA-A packs + x convert -----
__device__ __forceinline__ void transpose_tile(
    const float* __restrict__ in, ushort* __restrict__ out,
    int rows, int cols, int bx, int by, int tid)
{
    __shared__ float tile[32][33];
    const int tx = tid & 31, ty = tid >> 5;
#pragma unroll
    for (int i = 0; i < 32; i += 8)
        tile[ty + i][tx] = in[(size_t)(by + ty + i) * cols + bx + tx];
    __syncthreads();
#pragma unroll
    for (int i = 0; i < 32; i += 8)
        out[(size_t)(bx + ty + i) * rows + by + tx] = f2u(tile[tx][ty + i]);
}

__global__ __launch_bounds__(256) void prep_kernel(
    const float* __restrict__ x,
    const float* __restrict__ w_gate, const float* __restrict__ w_up,
    const float* __restrict__ w_down,
    const float* __restrict__ a_gate, const float* __restrict__ a_up,
    const float* __restrict__ a_down,
    ushort* __restrict__ XB, ushort* __restrict__ WGUA, ushort* __restrict__ WDA)
{
    const int bid = blockIdx.x, tid = threadIdx.x;
    if (bid < 4096) {
        transpose_tile(w_gate, WGUA, HDIM, FDIM, (bid & 127) * 32, (bid >> 7) * 32, tid);
    } else if (bid < 8192) {
        const int s = bid - 4096;
        transpose_tile(w_up, WGUA + (size_t)4096 * HDIM, HDIM, FDIM, (s & 127) * 32, (s >> 7) * 32, tid);
    } else if (bid < 12288) {
        const int s = bid - 8192;
        transpose_tile(w_down, WDA, FDIM, HDIM, (s & 31) * 32, (s >> 5) * 32, tid);
    } else if (bid < 12544) {
        const int row = bid - 12288;  // 0..255: e*32 + mat*16 + r
        const int e = row >> 5, mat = (row >> 4) & 1, r = row & 15;
        const float* src = (mat ? a_up : a_gate) + (size_t)e * HDIM * RLORA;
        ushort* dst = WGUA + (size_t)(8192 + row) * HDIM;
        for (int h = tid; h < HDIM; h += 256) dst[h] = f2u(src[h * RLORA + r]);
    } else if (bid < 12672) {
        const int row = bid - 12544;  // 0..127: e*16 + r
        const int e = row >> 4, r = row & 15;
        const float* src = a_down + (size_t)e * FDIM * RLORA;
        ushort* dst = WDA + (size_t)(1024 + row) * FDIM;
        for (int f = tid; f < FDIM; f += 256) dst[f] = f2u(src[f * RLORA + r]);
    } else {
        const int i = (bid - 12672) * 256 + tid;
        const float4 v = *reinterpret_cast<const float4*>(x + (size_t)i * 4);
        ushort4 o;
        o.x = f2u(v.x); o.y = f2u(v.y); o.z = f2u(v.z); o.w = f2u(v.w);
        *reinterpret_cast<ushort4*>(XB + (size_t)i * 4) = o;
    }
}

// ---- m97-style MFMA GEMM: 128x128 tile, BK=64, glds + XOR swizzle ----------
template <bool OUT_BF16, int SPLITK>
__global__ __launch_bounds__(256) void gemm128(
    const ushort* __restrict__ A, const ushort* __restrict__ Bt,
    void* __restrict__ Cv, int M, int N, int Kd, int ny)
{
    __shared__ __align__(16) ushort sA[128 * 64];
    __shared__ __align__(16) ushort sB[128 * 64];
    const int nwg = gridDim.x;
    const int q = nwg >> 3;  // nwg % 8 == 0 required
    const int wg = (blockIdx.x & 7) * q + (blockIdx.x >> 3);
    const int bn0 = (wg / ny) * 128, bm0 = (wg % ny) * 128;

    const int tid = threadIdx.x;
    const int wave = tid >> 6, lane = tid & 63;
    const int wm = wave >> 1, wn = wave & 1;

    f32x4 acc[4][4];
#pragma unroll
    for (int m = 0; m < 4; m++)
#pragma unroll
        for (int n = 0; n < 4; n++) acc[m][n] = (f32x4){0.f, 0.f, 0.f, 0.f};

    const int srow = tid >> 3;                       // 0..31 per pass
    const int sgrp8 = ((tid & 7) ^ (srow & 7)) * 8;  // pre-swizzled col (elems)

    const int kchunk = Kd / SPLITK;
    const int kbeg = blockIdx.z * kchunk, kend = kbeg + kchunk;
    for (int k0 = kbeg; k0 < kend; k0 += 64) {
#pragma unroll
        for (int i = 0; i < 4; i++) {
            const int row = i * 32 + srow;
            glds16(A + (size_t)(bm0 + row) * Kd + k0 + sgrp8, &sA[i * 2048 + wave * 512]);
            glds16(Bt + (size_t)(bn0 + row) * Kd + k0 + sgrp8, &sB[i * 2048 + wave * 512]);
        }
        __syncthreads();
#pragma unroll
        for (int kk = 0; kk < 2; kk++) {
            bf16x8 af[4], bfr[4];
            const int colb = (kk * 32 + (lane >> 4) * 8) * 2;
#pragma unroll
            for (int m = 0; m < 4; m++) {
                const int row = wm * 64 + m * 16 + (lane & 15);
                af[m] = *reinterpret_cast<const bf16x8*>(
                    (const char*)sA + row * 128 + (colb ^ ((row & 7) << 4)));
            }
#pragma unroll
            for (int n = 0; n < 4; n++) {
                const int row = wn * 64 + n * 16 + (lane & 15);
                bfr[n] = *reinterpret_cast<const bf16x8*>(
                    (const char*)sB + row * 128 + (colb ^ ((row & 7) << 4)));
            }
#pragma unroll
            for (int m = 0; m < 4; m++)
#pragma unroll
                for (int n = 0; n < 4; n++)
                    acc[m][n] = __builtin_amdgcn_mfma_f32_16x16x32_bf16(af[m], bfr[n], acc[m][n], 0, 0, 0);
        }
        __syncthreads();
    }

    const size_t zoff = (size_t)blockIdx.z * M * N;
    const int rg = lane & 15, qg = lane >> 4;
#pragma unroll
    for (int m = 0; m < 4; m++) {
#pragma unroll
        for (int n = 0; n < 4; n++) {
            const int row0 = bm0 + wm * 64 + m * 16 + qg * 4;
            const int col = bn0 + wn * 64 + n * 16 + rg;
#pragma unroll
            for (int j = 0; j < 4; j++) {
                if (OUT_BF16)
                    ((ushort*)Cv)[zoff + (size_t)(row0 + j) * N + col] = f2u(acc[m][n][j]);
                else
                    ((float*)Cv)[zoff + (size_t)(row0 + j) * N + col] = acc[m][n][j];
            }
        }
    }
}

// -------- Expert-grouped LoRA gate/up + SiLU -> ACT, B in registers ---------
// grid (NEXP, FDIM/512, ACT_NCHUNK); thread owns 2 consecutive f cols.
__global__ __launch_bounds__(256) void act3_kernel(
    const ushort* __restrict__ GU,   // [T, N1] bf16: G | U | XA
    const float* __restrict__ b_gate, const float* __restrict__ b_up,
    const int* __restrict__ CNT, const int* __restrict__ LIST,
    unsigned* __restrict__ ACT)      // [2048, FDIM/2] packed 2xbf16
{
    const int e = blockIdx.x, chunk = blockIdx.z;
    const int tid = threadIdx.x;
    const int f = blockIdx.y * 512 + tid * 2;

    float2 bg[16], bu[16];
    {
        const float* bgp = b_gate + (size_t)e * RLORA * FDIM + f;
        const float* bup = b_up + (size_t)e * RLORA * FDIM + f;
#pragma unroll
        for (int r = 0; r < 16; r++) {
            bg[r] = *reinterpret_cast<const float2*>(bgp + (size_t)r * FDIM);
            bu[r] = *reinterpret_cast<const float2*>(bup + (size_t)r * FDIM);
        }
    }

    const int n = __builtin_amdgcn_readfirstlane(CNT[e]);
    for (int i = chunk; i < n; i += ACT_NCHUNK) {
        const int p = __builtin_amdgcn_readfirstlane(LIST[e * 2048 + i]);
        const int t = p >> 1;
        const ushort* gurow = GU + (size_t)t * N1;
        // 32 xa bf16 (uniform address -> scalar loads)
        const unsigned* xap = (const unsigned*)(gurow + 8192 + e * 32);
        float xg[16], xu[16];
#pragma unroll
        for (int r = 0; r < 8; r++) {
            unsigned w = xap[r];
            xg[2 * r] = lo2f(w); xg[2 * r + 1] = hi2f(w);
        }
#pragma unroll
        for (int r = 0; r < 8; r++) {
            unsigned w = xap[8 + r];
            xu[2 * r] = lo2f(w); xu[2 * r + 1] = hi2f(w);
        }
        const unsigned gw = *(const unsigned*)(gurow + f);
        const unsigned uw = *(const unsigned*)(gurow + 4096 + f);
        float lg0 = 0.f, lg1 = 0.f, lu0 = 0.f, lu1 = 0.f;
#pragma unroll
        for (int r = 0; r < 16; r++) {
            lg0 += xg[r] * bg[r].x;
            lg1 += xg[r] * bg[r].y;
            lu0 += xu[r] * bu[r].x;
            lu1 += xu[r] * bu[r].y;
        }
        const float gate0 = lo2f(gw) + LSCALE * lg0;
        const float gate1 = hi2f(gw) + LSCALE * lg1;
        const float up0 = lo2f(uw) + LSCALE * lu0;
        const float up1 = hi2f(uw) + LSCALE * lu1;
        const float a0 = (gate0 / (1.f + expf(-gate0))) * up0;
        const float a1 = (gate1 / (1.f + expf(-gate1))) * up1;
        ACT[((size_t)p * FDIM + f) >> 1] = (unsigned)f2u(a0) | ((unsigned)f2u(a1) << 16);
    }
}

// -------- Combine: split-K reduce + LoRA-down expand + weighted sum ---------
__global__ __launch_bounds__(256) void combine2_kernel(
    const float* __restrict__ C2,    // [SPLITK2][2048][N2]: DOWN | AD partials
    const float* __restrict__ b_down, const int* __restrict__ SEL,
    const float* __restrict__ WTS, float* __restrict__ out)
{
    const int t = blockIdx.x, tid = threadIdx.x;
    const int e0 = SEL[t * 2 + 0], e1 = SEL[t * 2 + 1];
    const float w0 = WTS[t * 2 + 0], w1 = WTS[t * 2 + 1];
    __shared__ float ad0[16], ad1[16];
    if (tid < 16) {
        float v = 0.f;
#pragma unroll
        for (int z = 0; z < SPLITK2; z++)
            v += C2[((size_t)z * 2048 + 2 * t) * N2 + 1024 + e0 * 16 + tid];
        ad0[tid] = v;
    } else if (tid < 32) {
        float v = 0.f;
#pragma unroll
        for (int z = 0; z < SPLITK2; z++)
            v += C2[((size_t)z * 2048 + 2 * t + 1) * N2 + 1024 + e1 * 16 + (tid - 16)];
        ad1[tid - 16] = v;
    }
    __syncthreads();
    const float* B0 = b_down + (size_t)e0 * RLORA * HDIM;
    const float* B1 = b_down + (size_t)e1 * RLORA * HDIM;
    for (int h = tid; h < HDIM; h += 256) {
        float v0 = 0.f, v1 = 0.f;
#pragma unroll
        for (int z = 0; z < SPLITK2; z++) {
            v0 += C2[((size_t)z * 2048 + 2 * t) * N2 + h];
            v1 += C2[((size_t)z * 2048 + 2 * t + 1) * N2 + h];
        }
        float l0 = 0.f, l1 = 0.f;
#pragma unroll
        for (int r = 0; r < 16; r++) {
            l0 += ad0[r] * B0[r * HDIM + h];
            l1 += ad1[r] * B1[r * HDIM + h];
        }
        out[(size_t)t * HDIM + h] = w0 * (v0 + LSCALE * l0) + w1 * (v1 + LSCALE * l1);
    }
}

extern "C" void kernel_launch(void* const* d_in, const int* in_sizes, int n_in,
                              void* d_out, int out_size, void* d_ws, size_t ws_size,
                              hipStream_t stream) {
    (void)in_sizes; (void)n_in; (void)out_size; (void)ws_size;
    const float* x       = (const float*)d_in[0];
    const float* noise   = (const float*)d_in[1];
    const float* w_route = (const float*)d_in[2];
    const float* w_noise = (const float*)d_in[3];
    const float* w_gate  = (const float*)d_in[4];
    const float* w_up    = (const float*)d_in[5];
    const float* w_down  = (const float*)d_in[6];
    const float* a_gate  = (const float*)d_in[7];
    const float* b_gate  = (const float*)d_in[8];
    const float* a_up    = (const float*)d_in[9];
    const float* b_up    = (const float*)d_in[10];
    const float* a_down  = (const float*)d_in[11];
    const float* b_down  = (const float*)d_in[12];
    float* out    = (float*)d_out;
    float* rl_out = out + (size_t)T_TOK * HDIM;

    char* ws = (char*)d_ws;
    float*  C2   = (float*)(ws);                          // [4][2048][1152] fp32 = 36 MB
    ushort* WGUA = (ushort*)(ws + (size_t)(18 << 20));    // [8448][1024] bf16 = 16.5 MB (dead before C2 written)
    bf16*   ACT  = (bf16*)(ws + (size_t)(36 << 20));      // [2048][4096] bf16 = 16 MB
    ushort* WDA  = (ushort*)(ws + (size_t)(52 << 20));    // [1152][4096] bf16 = 9 MB
    ushort* XB   = (ushort*)(ws + (size_t)(62 << 20));    // [1024][1024] bf16 = 2 MB
    ushort* C1b  = (ushort*)(ws + (size_t)(64 << 20));    // [1024][8448] bf16 = 16.5 MB
    int*    LIST = (int*)(ws + (size_t)(81 << 20));       // 64 KB
    int*    CNT  = (int*)(ws + (size_t)(81 << 20) + (1 << 17));
    int*    SEL  = (int*)(ws + (size_t)(81 << 20) + (1 << 17) + 4096);
    float*  WTS  = (float*)(ws + (size_t)(81 << 20) + (1 << 17) + 16384);

    hipMemsetAsync(CNT, 0, NEXP * sizeof(int), stream);

    router_kernel<<<T_TOK, 256, 0, stream>>>(x, noise, w_route, w_noise, rl_out, SEL, WTS, CNT, LIST);

    prep_kernel<<<13696, 256, 0, stream>>>(x, w_gate, w_up, w_down, a_gate, a_up, a_down,
                                           XB, WGUA, WDA);

    // GEMM1: C1b[1024][8448] = XB @ WGUA^T  (bf16 out). grid 66*8=528 (%8==0)
    gemm128<true, 1><<<dim3((N1 / 128) * (T_TOK / 128), 1, 1), 256, 0, stream>>>(
        XB, WGUA, C1b, T_TOK, N1, HDIM, T_TOK / 128);

    act3_kernel<<<dim3(NEXP, FDIM / 512, ACT_NCHUNK), 256, 0, stream>>>(
        C1b, b_gate, b_up, CNT, LIST, (unsigned*)ACT);

    // GEMM2: C2[z][2048][1152] = ACT @ WDA^T partials. grid 9*16=144 (%8==0), z=4
    gemm128<false, SPLITK2><<<dim3((N2 / 128) * (2 * T_TOK / 128), 1, SPLITK2), 256, 0, stream>>>(
        (const ushort*)ACT, WDA, C2, 2 * T_TOK, N2, FDIM, 2 * T_TOK / 128);

    combine2_kernel<<<T_TOK, 256, 0, stream>>>(C2, b_down, SEL, WTS, out);
}